// Round 22
// baseline (64.897 us; speedup 1.0000x reference)
//
#include <hip/hip_runtime.h>
#include <math.h>

#define NX 128
#define NY 128
#define NZ 64
#define NVOX (NX * NY * NZ)   // 1048576 = 1<<20
#define NC 32
#define FH 120
#define FW 160
#define FHW (FH * FW)         // 19200
#define VOXSZ 0.04f
#define NB 2

// Single fused kernel. Block = 256 consecutive voxels of one batch.
// Phase 1: each thread projects its voxel (PINNED R14 pipeline: f32,
//          contract off, pairwise association, IEEE div, rndne -- bit-exact),
//          writes idx to LDS and the valid-plane output.
// Phase 2: 8 passes; thread t -> channel c = p*4 + (t>>6), lane = t&63;
//          gathers 4 scalars from ONE feat plane via LDS idx, stores one
//          float4 -> per-wave 1KB contiguous bursts in a single plane
//          (fill-kernel store shape), only 4 concurrent streams.
// XCD batch-partition swizzle (R21): blockIdx%8 in {0..3} -> b=0 else b=1,
// halving each XCD's feat working set (2.4MB < 4MB L2).
__global__ __launch_bounds__(256) void voxel_backproject_kernel(
    const float* __restrict__ proj,
    const float* __restrict__ feat,
    const float* __restrict__ origin,
    float* __restrict__ out)
{
#pragma clang fp contract(off)
    __shared__ int idx_lds[256];

    const int t  = threadIdx.x;
    const int q8 = blockIdx.x >> 3;
    const int r8 = blockIdx.x & 7;
    const int b  = r8 >> 2;
    const int g  = q8 * 4 + (r8 & 3);                 // 0..4095 within batch
    const int n0blk = g * 256;                        // first voxel of block
    const int n  = n0blk + t;
    const int i = n >> 13;
    const int j = (n >> 6) & (NY - 1);
    const int k = n & (NZ - 1);

    // ---- Phase 1: projection (bit-exact pinned pipeline) ----
    const float* P = proj + b * 12;
    const float ox = origin[b * 3 + 0];
    const float oy = origin[b * 3 + 1];
    const float oz = origin[b * 3 + 2];

    const float wx = (float)i * VOXSZ + ox;
    const float wy = (float)j * VOXSZ + oy;
    const float wz = (float)k * VOXSZ + oz;

    const float tx = P[0] * wx + P[1] * wy;
    const float ty = P[4] * wx + P[5] * wy;
    const float tz = P[8] * wx + P[9] * wy;

    const float cx = tx + (P[2]  * wz + P[3]);
    const float cy = ty + (P[6]  * wz + P[7]);
    const float cz = tz + (P[10] * wz + P[11]);

    const float qx = cx / cz;
    const float qy = cy / cz;
    const int px = __float2int_rn(qx);
    const int py = __float2int_rn(qy);
    const bool v = (px >= 0) & (py >= 0) & (px < FW) & (py < FH) & (cz > 0.0f);

    idx_lds[t] = v ? (py * FW + px) : -1;
    out[(size_t)NB * NC * NVOX + (size_t)b * NVOX + n] = v ? 1.0f : 0.0f;

    __syncthreads();

    // ---- Phase 2: channel-major gather + contiguous float4 stores ----
    const int c0   = t >> 6;                          // 0..3
    const int lane = t & 63;
    const int4 id4 = ((const int4*)idx_lds)[lane];    // 4 consecutive voxels
    const float* fbase = feat + (size_t)b * NC * FHW;
    float* obase = out + (size_t)b * NC * NVOX + n0blk + lane * 4;

    #pragma unroll
    for (int p = 0; p < 8; ++p) {
        const int c = p * 4 + c0;
        const float* fp = fbase + (size_t)c * FHW;
        float4 r;
        r.x = (id4.x >= 0) ? fp[id4.x] : 0.0f;
        r.y = (id4.y >= 0) ? fp[id4.y] : 0.0f;
        r.z = (id4.z >= 0) ? fp[id4.z] : 0.0f;
        r.w = (id4.w >= 0) ? fp[id4.w] : 0.0f;
        *(float4*)(obase + (size_t)c * NVOX) = r;
    }
}

extern "C" void kernel_launch(void* const* d_in, const int* in_sizes, int n_in,
                              void* d_out, int out_size, void* d_ws, size_t ws_size,
                              hipStream_t stream) {
    const float* proj   = (const float*)d_in[0];
    const float* feat   = (const float*)d_in[1];
    const float* origin = (const float*)d_in[2];
    float* out = (float*)d_out;

    const int total = NB * NVOX;                      // 2097152
    voxel_backproject_kernel<<<total / 256, 256, 0, stream>>>(proj, feat, origin, out);
}